// Round 6
// baseline (178.957 us; speedup 1.0000x reference)
//
#include <hip/hip_runtime.h>

#define BATCH 2
#define S_LEN 2048
#define NHEADS 16
#define DKV 64
#define HID 1024

typedef __attribute__((ext_vector_type(8))) short s16x8;
typedef __attribute__((ext_vector_type(4))) float f32x4;

__device__ inline unsigned short f2bf(float f) {
    union { float f; unsigned int u; } v; v.f = f;
    unsigned int r = v.u + 0x7fffu + ((v.u >> 16) & 1u);
    return (unsigned short)(r >> 16);
}

__device__ inline s16x8 pack8(float4 a, float4 b) {
    s16x8 r;
    r[0] = (short)f2bf(a.x); r[1] = (short)f2bf(a.y);
    r[2] = (short)f2bf(a.z); r[3] = (short)f2bf(a.w);
    r[4] = (short)f2bf(b.x); r[5] = (short)f2bf(b.y);
    r[6] = (short)f2bf(b.z); r[7] = (short)f2bf(b.w);
    return r;
}

__device__ inline void gload_lds16(const void* g, void* l) {
    __builtin_amdgcn_global_load_lds(
        (const __attribute__((address_space(1))) void*)g,
        (__attribute__((address_space(3))) void*)l, 16, 0, 0);
}

// fp32 -> bf16 elementwise (8 elems/thread)
__global__ __launch_bounds__(256)
void f32_to_bf16_kernel(const float* __restrict__ in, unsigned short* __restrict__ out, int n8) {
    int i = blockIdx.x * 256 + threadIdx.x;
    if (i < n8) {
        const float4* p = (const float4*)(in + (size_t)i * 8);
        float4 a = p[0], b = p[1];
        *(s16x8*)(out + (size_t)i * 8) = pack8(a, b);
    }
}

// fp32 [K][N] -> bf16 [N][K]
__global__ __launch_bounds__(256)
void transpose_bf16_kernel(const float* __restrict__ in, unsigned short* __restrict__ out,
                           int K, int N) {
    __shared__ float tile[32][33];
    int n0 = blockIdx.x * 32;
    int k0 = blockIdx.y * 32;
    int tx = threadIdx.x, ty = threadIdx.y;
    for (int i = ty; i < 32; i += 8)
        tile[i][tx] = in[(size_t)(k0 + i) * N + n0 + tx];
    __syncthreads();
    for (int i = ty; i < 32; i += 8)
        out[(size_t)(n0 + i) * K + k0 + tx] = f2bf(tile[tx][i]);
}

// C[M][N] = A[M][K](bf16) * Bt[N][K](bf16)^T + bias. m97 structure, BM=128.
template<int OUT_BF16>
__global__ __launch_bounds__(256)
void gemm_kernel(const unsigned short* __restrict__ A, const unsigned short* __restrict__ Bt,
                 const float* __restrict__ bias, void* __restrict__ Cout,
                 int M, int N, int K) {
    __shared__ __align__(16) unsigned short As[128 * 32];
    __shared__ __align__(16) unsigned short Bs[128 * 32];

    const int tid  = threadIdx.x;
    const int lane = tid & 63;
    const int wv   = tid >> 6;
    const int wr   = wv >> 1, wc = wv & 1;
    const int m0   = blockIdx.y * 128, n0 = blockIdx.x * 128;

    const int lr = lane & 15;
    const int lg = lane >> 4;
    const int lk = lg * 8;

    const int srow = lane >> 2;
    const int scol = (lane & 3) * 8;

    f32x4 acc[4][4] = {};

    for (int k0 = 0; k0 < K; k0 += 32) {
        __syncthreads();
        #pragma unroll
        for (int l = 0; l < 2; l++) {
            const int r0 = wv * 32 + l * 16;
            gload_lds16(A  + (size_t)(m0 + r0 + srow) * K + k0 + scol, &As[r0 * 32]);
            gload_lds16(Bt + (size_t)(n0 + r0 + srow) * K + k0 + scol, &Bs[r0 * 32]);
        }
        __syncthreads();

        s16x8 af[4], bfr[4];
        #pragma unroll
        for (int mi = 0; mi < 4; mi++)
            af[mi] = *(const s16x8*)&As[(wr * 64 + mi * 16 + lr) * 32 + lk];
        #pragma unroll
        for (int ni = 0; ni < 4; ni++)
            bfr[ni] = *(const s16x8*)&Bs[(wc * 64 + ni * 16 + lr) * 32 + lk];
        #pragma unroll
        for (int mi = 0; mi < 4; mi++)
            #pragma unroll
            for (int ni = 0; ni < 4; ni++)
                acc[mi][ni] = __builtin_amdgcn_mfma_f32_16x16x32_bf16(af[mi], bfr[ni], acc[mi][ni], 0, 0, 0);
    }

    #pragma unroll
    for (int mi = 0; mi < 4; mi++) {
        #pragma unroll
        for (int ni = 0; ni < 4; ni++) {
            int col = n0 + wc * 64 + ni * 16 + lr;
            float bv = bias[col];
            #pragma unroll
            for (int r = 0; r < 4; r++) {
                int row = m0 + wr * 64 + mi * 16 + lg * 4 + r;
                float v = acc[mi][ni][r] + bv;
                if (OUT_BF16)
                    ((unsigned short*)Cout)[(size_t)row * N + col] = f2bf(v);
                else
                    ((float*)Cout)[(size_t)row * N + col] = v;
            }
        }
    }
}

// BM=64 variant for the skinny projection GEMM (better occupancy at N=1024).
template<int OUT_BF16>
__global__ __launch_bounds__(256)
void gemm64_kernel(const unsigned short* __restrict__ A, const unsigned short* __restrict__ Bt,
                   const float* __restrict__ bias, void* __restrict__ Cout,
                   int M, int N, int K) {
    __shared__ __align__(16) unsigned short As[64 * 32];
    __shared__ __align__(16) unsigned short Bs[128 * 32];

    const int tid  = threadIdx.x;
    const int lane = tid & 63;
    const int wv   = tid >> 6;
    const int wr   = wv >> 1, wc = wv & 1;
    const int m0   = blockIdx.y * 64, n0 = blockIdx.x * 128;

    const int lr = lane & 15;
    const int lg = lane >> 4;
    const int lk = lg * 8;

    const int srow = lane >> 2;
    const int scol = (lane & 3) * 8;

    const int arow = tid >> 2;
    const int acol = (tid & 3) * 8;

    f32x4 acc[2][4] = {};

    for (int k0 = 0; k0 < K; k0 += 32) {
        __syncthreads();
        gload_lds16(A + (size_t)(m0 + arow) * K + k0 + acol, &As[(arow & ~3) * 32]);
        #pragma unroll
        for (int l = 0; l < 2; l++) {
            const int r0 = wv * 32 + l * 16;
            gload_lds16(Bt + (size_t)(n0 + r0 + srow) * K + k0 + scol, &Bs[r0 * 32]);
        }
        __syncthreads();

        s16x8 af[2], bfr[4];
        #pragma unroll
        for (int mi = 0; mi < 2; mi++)
            af[mi] = *(const s16x8*)&As[(wr * 32 + mi * 16 + lr) * 32 + lk];
        #pragma unroll
        for (int ni = 0; ni < 4; ni++)
            bfr[ni] = *(const s16x8*)&Bs[(wc * 64 + ni * 16 + lr) * 32 + lk];
        #pragma unroll
        for (int mi = 0; mi < 2; mi++)
            #pragma unroll
            for (int ni = 0; ni < 4; ni++)
                acc[mi][ni] = __builtin_amdgcn_mfma_f32_16x16x32_bf16(af[mi], bfr[ni], acc[mi][ni], 0, 0, 0);
    }

    #pragma unroll
    for (int mi = 0; mi < 2; mi++) {
        #pragma unroll
        for (int ni = 0; ni < 4; ni++) {
            int col = n0 + wc * 64 + ni * 16 + lr;
            float bv = bias[col];
            #pragma unroll
            for (int r = 0; r < 4; r++) {
                int row = m0 + wr * 32 + mi * 16 + lg * 4 + r;
                float v = acc[mi][ni][r] + bv;
                if (OUT_BF16)
                    ((unsigned short*)Cout)[(size_t)row * N + col] = f2bf(v);
                else
                    ((float*)Cout)[(size_t)row * N + col] = v;
            }
        }
    }
}

// qkv bf16 [B*S][3H]. out bf16 [B*S][H].
// Block: 128 q-rows (4 waves x 32), KV tile 64. Blocks launched biggest-first.
// Constant-shift softmax p = exp2(s*c1 + c0); l via ones-row MFMA.
// Ks: linear LDS + XOR-swizzled source/read.
__global__ __launch_bounds__(256)
void attn_kernel(const unsigned short* __restrict__ qkv, unsigned short* __restrict__ out) {
    __shared__ __align__(16) unsigned short Ks[64 * 64];
    __shared__ __align__(16) unsigned short Vt[80][72];
    __shared__ __align__(16) unsigned short Ps[4][32][72];

    const int tid  = threadIdx.x;
    const int lane = tid & 63;
    const int w    = tid >> 6;
    const int head = blockIdx.y;
    const int b    = blockIdx.z;

    const size_t rowbase = (size_t)b * S_LEN;
    const int hoff = head * DKV;

    const int lr = lane & 15;
    const int lg = lane >> 4;
    const int lk = lg * 8;

    const int krow   = lane >> 3;                    // 0..7
    const int kchunk = ((lane & 7) ^ krow) * 8;      // pre-swizzled source column

    // ones/zeros rows for the l-accumulating V fragment
    for (int i = tid; i < 16 * 72; i += 256) {
        int rr = i / 72, cc = i % 72;
        Vt[64 + rr][cc] = (rr == 0 && cc < 64) ? (unsigned short)0x3F80 : (unsigned short)0;
    }

    const int qb = 15 - (int)blockIdx.x;   // biggest blocks first
    const int q0 = qb * 128;
    const int nt = 2 * qb + 2;

    // Q fragments: wave w owns rows q0 + w*32 .. +31
    s16x8 qf[2][2];
    #pragma unroll
    for (int mi = 0; mi < 2; mi++) {
        const unsigned short* qp = qkv + (rowbase + q0 + w * 32 + mi * 16 + lr) * (3 * HID) + hoff;
        qf[mi][0] = *(const s16x8*)(qp + lk);
        qf[mi][1] = *(const s16x8*)(qp + 32 + lk);
    }

    f32x4 o[2][4] = {};
    f32x4 o4[2] = {};

    for (int tt = 0; tt < nt; tt++) {
        const int j0 = tt * 64;
        __syncthreads();
        // stage K [64][64] linear, source pre-swizzled
        #pragma unroll
        for (int l = 0; l < 2; l++) {
            const int r0 = (w * 2 + l) * 8;
            gload_lds16(qkv + (rowbase + j0 + r0 + krow) * (3 * HID) + HID + hoff + kchunk,
                        &Ks[r0 * 64]);
        }
        // stage V transposed: lane = key
        {
            const unsigned short* vp = qkv + (rowbase + j0 + lane) * (3 * HID) + 2 * HID + hoff + w * 16;
            s16x8 v0 = *(const s16x8*)vp;
            s16x8 v1 = *(const s16x8*)(vp + 8);
            #pragma unroll
            for (int i = 0; i < 8; i++) Vt[w * 16 + i][lane] = (unsigned short)v0[i];
            #pragma unroll
            for (int i = 0; i < 8; i++) Vt[w * 16 + 8 + i][lane] = (unsigned short)v1[i];
        }
        __syncthreads();

        // S = Q K^T  (32 q-rows x 64 keys per wave)
        f32x4 sf[2][4] = {};
        #pragma unroll
        for (int kt = 0; kt < 2; kt++)
            #pragma unroll
            for (int ni = 0; ni < 4; ni++) {
                s16x8 kb = *(const s16x8*)&Ks[(ni * 16 + lr) * 64 + (((kt * 4 + lg) ^ (lr & 7)) * 8)];
                #pragma unroll
                for (int mi = 0; mi < 2; mi++)
                    sf[mi][ni] = __builtin_amdgcn_mfma_f32_16x16x32_bf16(qf[mi][kt], kb, sf[mi][ni], 0, 0, 0);
            }

        const bool needmask = (tt >= nt - 2);
        // p = exp2(s*0.125*log2e - 12*log2e): no max tracking
        #pragma unroll
        for (int mi = 0; mi < 2; mi++)
            #pragma unroll
            for (int ni = 0; ni < 4; ni++)
                #pragma unroll
                for (int r = 0; r < 4; r++) {
                    float s = sf[mi][ni][r];
                    if (needmask) {
                        int qi = q0 + w * 32 + mi * 16 + lg * 4 + r;
                        if (j0 + ni * 16 + lr > qi) s = -INFINITY;
                    }
                    float p = exp2f(__fmaf_rn(s, 0.18033688f, -17.3123405f));
                    union { float f; unsigned int u; } cv; cv.f = p;
                    Ps[w][mi * 16 + lg * 4 + r][ni * 16 + lr] = (unsigned short)(cv.u >> 16);
                }

        // O += P V ; l via ones-row fragment
        #pragma unroll
        for (int kt = 0; kt < 2; kt++) {
            s16x8 pa0 = *(const s16x8*)&Ps[w][lr][kt * 32 + lk];
            s16x8 pa1 = *(const s16x8*)&Ps[w][16 + lr][kt * 32 + lk];
            #pragma unroll
            for (int dt = 0; dt < 4; dt++) {
                s16x8 vb = *(const s16x8*)&Vt[dt * 16 + lr][kt * 32 + lk];
                o[0][dt] = __builtin_amdgcn_mfma_f32_16x16x32_bf16(pa0, vb, o[0][dt], 0, 0, 0);
                o[1][dt] = __builtin_amdgcn_mfma_f32_16x16x32_bf16(pa1, vb, o[1][dt], 0, 0, 0);
            }
            s16x8 vb4 = *(const s16x8*)&Vt[64 + lr][kt * 32 + lk];
            o4[0] = __builtin_amdgcn_mfma_f32_16x16x32_bf16(pa0, vb4, o4[0], 0, 0, 0);
            o4[1] = __builtin_amdgcn_mfma_f32_16x16x32_bf16(pa1, vb4, o4[1], 0, 0, 0);
        }
    }

    // normalize + write bf16 (l lives in lanes lr==0 of each lane-group)
    #pragma unroll
    for (int mi = 0; mi < 2; mi++)
        #pragma unroll
        for (int r = 0; r < 4; r++) {
            float l = __shfl(o4[mi][r], lane & 48);
            float invl = 1.0f / l;
            int qi = q0 + w * 32 + mi * 16 + lg * 4 + r;
            #pragma unroll
            for (int dt = 0; dt < 4; dt++)
                out[(rowbase + qi) * HID + hoff + dt * 16 + lr] = f2bf(o[mi][dt][r] * invl);
        }
}

extern "C" void kernel_launch(void* const* d_in, const int* in_sizes, int n_in,
                              void* d_out, int out_size, void* d_ws, size_t ws_size,
                              hipStream_t stream) {
    const float* x      = (const float*)d_in[0];
    const float* w_attn = (const float*)d_in[1];
    const float* b_attn = (const float*)d_in[2];
    const float* w_proj = (const float*)d_in[3];
    const float* b_proj = (const float*)d_in[4];
    float* out = (float*)d_out;

    char* ws = (char*)d_ws;
    unsigned short* qkv      = (unsigned short*)(ws);               // 24 MB
    unsigned short* waT      = (unsigned short*)(ws + 25165824);    // 6 MB
    unsigned short* wpT      = (unsigned short*)(ws + 31457280);    // 2 MB
    unsigned short* attn_out = (unsigned short*)(ws + 33554432);    // 8 MB (bf16)
    unsigned short* xb       = (unsigned short*)(ws + 41943040);    // 8 MB (bf16)

    const int M = BATCH * S_LEN;   // 4096

    f32_to_bf16_kernel<<<dim3((M * HID / 8 + 255) / 256), 256, 0, stream>>>(x, xb, M * HID / 8);

    dim3 tb(32, 8);
    transpose_bf16_kernel<<<dim3(3 * HID / 32, HID / 32), tb, 0, stream>>>(w_attn, waT, HID, 3 * HID);
    transpose_bf16_kernel<<<dim3(HID / 32, HID / 32), tb, 0, stream>>>(w_proj, wpT, HID, HID);

    gemm_kernel<1><<<dim3(3 * HID / 128, M / 128), 256, 0, stream>>>(
        xb, waT, b_attn, (void*)qkv, M, 3 * HID, HID);

    attn_kernel<<<dim3(16, NHEADS, BATCH), 256, 0, stream>>>(qkv, attn_out);

    gemm64_kernel<0><<<dim3(HID / 128, M / 64), 256, 0, stream>>>(
        attn_out, wpT, b_proj, out, M, HID, HID);
}

// Round 7
// 138.670 us; speedup vs baseline: 1.2905x; 1.2905x over previous
//
#include <hip/hip_runtime.h>

#define BATCH 2
#define S_LEN 2048
#define NHEADS 16
#define DKV 64
#define HID 1024

typedef __attribute__((ext_vector_type(8))) short s16x8;
typedef __attribute__((ext_vector_type(4))) float f32x4;

__device__ inline unsigned short f2bf(float f) {
    union { float f; unsigned int u; } v; v.f = f;
    unsigned int r = v.u + 0x7fffu + ((v.u >> 16) & 1u);
    return (unsigned short)(r >> 16);
}

__device__ inline s16x8 pack8(float4 a, float4 b) {
    s16x8 r;
    r[0] = (short)f2bf(a.x); r[1] = (short)f2bf(a.y);
    r[2] = (short)f2bf(a.z); r[3] = (short)f2bf(a.w);
    r[4] = (short)f2bf(b.x); r[5] = (short)f2bf(b.y);
    r[6] = (short)f2bf(b.z); r[7] = (short)f2bf(b.w);
    return r;
}

__device__ inline void gload_lds16(const void* g, void* l) {
    __builtin_amdgcn_global_load_lds(
        (const __attribute__((address_space(1))) void*)g,
        (__attribute__((address_space(3))) void*)l, 16, 0, 0);
}

// fp32 -> bf16 elementwise (8 elems/thread)
__global__ __launch_bounds__(256)
void f32_to_bf16_kernel(const float* __restrict__ in, unsigned short* __restrict__ out, int n8) {
    int i = blockIdx.x * 256 + threadIdx.x;
    if (i < n8) {
        const float4* p = (const float4*)(in + (size_t)i * 8);
        float4 a = p[0], b = p[1];
        *(s16x8*)(out + (size_t)i * 8) = pack8(a, b);
    }
}

// fp32 [K][N] -> bf16 [N][K]
__global__ __launch_bounds__(256)
void transpose_bf16_kernel(const float* __restrict__ in, unsigned short* __restrict__ out,
                           int K, int N) {
    __shared__ float tile[32][33];
    int n0 = blockIdx.x * 32;
    int k0 = blockIdx.y * 32;
    int tx = threadIdx.x, ty = threadIdx.y;
    for (int i = ty; i < 32; i += 8)
        tile[i][tx] = in[(size_t)(k0 + i) * N + n0 + tx];
    __syncthreads();
    for (int i = ty; i < 32; i += 8)
        out[(size_t)(n0 + i) * K + k0 + tx] = f2bf(tile[tx][i]);
}

// V-part of qkv [B*S][3H] -> vT [B][HID][S]  (per-batch [S][HID] transpose, bf16)
__global__ __launch_bounds__(256)
void vtrans_kernel(const unsigned short* __restrict__ qkv, unsigned short* __restrict__ vT) {
    __shared__ unsigned short tile[32][33];
    int c0 = blockIdx.x * 32;           // d-col within HID
    int s0 = blockIdx.y * 32;           // seq
    int b  = blockIdx.z;
    int tx = threadIdx.x, ty = threadIdx.y;
    const size_t rowbase = (size_t)b * S_LEN;
    for (int i = ty; i < 32; i += 8)
        tile[i][tx] = qkv[(rowbase + s0 + i) * (3 * HID) + 2 * HID + c0 + tx];
    __syncthreads();
    for (int i = ty; i < 32; i += 8)
        vT[((size_t)b * HID + c0 + i) * S_LEN + s0 + tx] = tile[tx][i];
}

// C[M][N] = A[M][K](bf16) * Bt[N][K](bf16)^T + bias. m97 structure, BM=128.
template<int OUT_BF16>
__global__ __launch_bounds__(256)
void gemm_kernel(const unsigned short* __restrict__ A, const unsigned short* __restrict__ Bt,
                 const float* __restrict__ bias, void* __restrict__ Cout,
                 int M, int N, int K) {
    __shared__ __align__(16) unsigned short As[128 * 32];
    __shared__ __align__(16) unsigned short Bs[128 * 32];

    const int tid  = threadIdx.x;
    const int lane = tid & 63;
    const int wv   = tid >> 6;
    const int wr   = wv >> 1, wc = wv & 1;
    const int m0   = blockIdx.y * 128, n0 = blockIdx.x * 128;

    const int lr = lane & 15;
    const int lg = lane >> 4;
    const int lk = lg * 8;

    const int srow = lane >> 2;
    const int scol = (lane & 3) * 8;

    f32x4 acc[4][4] = {};

    for (int k0 = 0; k0 < K; k0 += 32) {
        __syncthreads();
        #pragma unroll
        for (int l = 0; l < 2; l++) {
            const int r0 = wv * 32 + l * 16;
            gload_lds16(A  + (size_t)(m0 + r0 + srow) * K + k0 + scol, &As[r0 * 32]);
            gload_lds16(Bt + (size_t)(n0 + r0 + srow) * K + k0 + scol, &Bs[r0 * 32]);
        }
        __syncthreads();

        s16x8 af[4], bfr[4];
        #pragma unroll
        for (int mi = 0; mi < 4; mi++)
            af[mi] = *(const s16x8*)&As[(wr * 64 + mi * 16 + lr) * 32 + lk];
        #pragma unroll
        for (int ni = 0; ni < 4; ni++)
            bfr[ni] = *(const s16x8*)&Bs[(wc * 64 + ni * 16 + lr) * 32 + lk];
        #pragma unroll
        for (int mi = 0; mi < 4; mi++)
            #pragma unroll
            for (int ni = 0; ni < 4; ni++)
                acc[mi][ni] = __builtin_amdgcn_mfma_f32_16x16x32_bf16(af[mi], bfr[ni], acc[mi][ni], 0, 0, 0);
    }

    #pragma unroll
    for (int mi = 0; mi < 4; mi++) {
        #pragma unroll
        for (int ni = 0; ni < 4; ni++) {
            int col = n0 + wc * 64 + ni * 16 + lr;
            float bv = bias[col];
            #pragma unroll
            for (int r = 0; r < 4; r++) {
                int row = m0 + wr * 64 + mi * 16 + lg * 4 + r;
                float v = acc[mi][ni][r] + bv;
                if (OUT_BF16)
                    ((unsigned short*)Cout)[(size_t)row * N + col] = f2bf(v);
                else
                    ((float*)Cout)[(size_t)row * N + col] = v;
            }
        }
    }
}

// BM=64 variant for the skinny projection GEMM.
template<int OUT_BF16>
__global__ __launch_bounds__(256)
void gemm64_kernel(const unsigned short* __restrict__ A, const unsigned short* __restrict__ Bt,
                   const float* __restrict__ bias, void* __restrict__ Cout,
                   int M, int N, int K) {
    __shared__ __align__(16) unsigned short As[64 * 32];
    __shared__ __align__(16) unsigned short Bs[128 * 32];

    const int tid  = threadIdx.x;
    const int lane = tid & 63;
    const int wv   = tid >> 6;
    const int wr   = wv >> 1, wc = wv & 1;
    const int m0   = blockIdx.y * 64, n0 = blockIdx.x * 128;

    const int lr = lane & 15;
    const int lg = lane >> 4;
    const int lk = lg * 8;

    const int srow = lane >> 2;
    const int scol = (lane & 3) * 8;

    const int arow = tid >> 2;
    const int acol = (tid & 3) * 8;

    f32x4 acc[2][4] = {};

    for (int k0 = 0; k0 < K; k0 += 32) {
        __syncthreads();
        gload_lds16(A + (size_t)(m0 + arow) * K + k0 + acol, &As[(arow & ~3) * 32]);
        #pragma unroll
        for (int l = 0; l < 2; l++) {
            const int r0 = wv * 32 + l * 16;
            gload_lds16(Bt + (size_t)(n0 + r0 + srow) * K + k0 + scol, &Bs[r0 * 32]);
        }
        __syncthreads();

        s16x8 af[2], bfr[4];
        #pragma unroll
        for (int mi = 0; mi < 2; mi++)
            af[mi] = *(const s16x8*)&As[(wr * 32 + mi * 16 + lr) * 32 + lk];
        #pragma unroll
        for (int ni = 0; ni < 4; ni++)
            bfr[ni] = *(const s16x8*)&Bs[(wc * 64 + ni * 16 + lr) * 32 + lk];
        #pragma unroll
        for (int mi = 0; mi < 2; mi++)
            #pragma unroll
            for (int ni = 0; ni < 4; ni++)
                acc[mi][ni] = __builtin_amdgcn_mfma_f32_16x16x32_bf16(af[mi], bfr[ni], acc[mi][ni], 0, 0, 0);
    }

    #pragma unroll
    for (int mi = 0; mi < 2; mi++) {
        #pragma unroll
        for (int ni = 0; ni < 4; ni++) {
            int col = n0 + wc * 64 + ni * 16 + lr;
            float bv = bias[col];
            #pragma unroll
            for (int r = 0; r < 4; r++) {
                int row = m0 + wr * 32 + mi * 16 + lg * 4 + r;
                float v = acc[mi][ni][r] + bv;
                if (OUT_BF16)
                    ((unsigned short*)Cout)[(size_t)row * N + col] = f2bf(v);
                else
                    ((float*)Cout)[(size_t)row * N + col] = v;
            }
        }
    }
}

// qkv bf16 [B*S][3H], vT bf16 [B][HID][S]. out bf16 [B*S][H].
// Block: 64 q-rows (4 waves x 16), KV tile 64. Triangle pairing {p, 31-p}.
// K and V^T both staged via global_load_lds into linear [64][64] with
// both-sides XOR swizzle. Constant-shift softmax p = exp2(s*c1+c0);
// l via ones-row MFMA fragment.
__global__ __launch_bounds__(256)
void attn_kernel(const unsigned short* __restrict__ qkv, const unsigned short* __restrict__ vT,
                 unsigned short* __restrict__ out) {
    __shared__ __align__(16) unsigned short Ks[64 * 64];
    __shared__ __align__(16) unsigned short Vs[64 * 64];
    __shared__ __align__(16) unsigned short Ones[16][72];
    __shared__ __align__(16) unsigned short Ps[4][16][72];

    const int tid  = threadIdx.x;
    const int lane = tid & 63;
    const int w    = tid >> 6;
    const int head = blockIdx.y;
    const int b    = blockIdx.z;

    const size_t rowbase = (size_t)b * S_LEN;
    const int hoff = head * DKV;

    const int lr = lane & 15;
    const int lg = lane >> 4;
    const int lk = lg * 8;

    const int krow   = lane >> 3;                    // 0..7
    const int kchunk = ((lane & 7) ^ krow) * 8;      // pre-swizzled source column

    // ones row for the l-accumulating fragment (row 0 = 1.0, rows 1..15 = 0)
    for (int i = tid; i < 16 * 72; i += 256) {
        int rr = i / 72, cc = i % 72;
        Ones[rr][cc] = (rr == 0 && cc < 64) ? (unsigned short)0x3F80 : (unsigned short)0;
    }

    #pragma unroll
    for (int panel = 0; panel < 2; panel++) {
        const int qb = (panel == 0) ? (int)blockIdx.x : (31 - (int)blockIdx.x);
        const int q0 = qb * 64;
        const int nt = qb + 1;

        s16x8 qf[2];
        {
            const unsigned short* qp = qkv + (rowbase + q0 + w * 16 + lr) * (3 * HID) + hoff;
            qf[0] = *(const s16x8*)(qp + lk);
            qf[1] = *(const s16x8*)(qp + 32 + lk);
        }

        f32x4 o[4] = {};
        f32x4 o4 = {};

        for (int tt = 0; tt < nt; tt++) {
            const int j0 = tt * 64;
            __syncthreads();
            // stage K [64 keys][64 d] and V^T [64 d][64 keys], both linear + pre-swizzled src
            #pragma unroll
            for (int l = 0; l < 2; l++) {
                const int r0 = (w * 2 + l) * 8;
                gload_lds16(qkv + (rowbase + j0 + r0 + krow) * (3 * HID) + HID + hoff + kchunk,
                            &Ks[r0 * 64]);
                gload_lds16(vT + ((size_t)b * HID + hoff + r0 + krow) * S_LEN + j0 + kchunk,
                            &Vs[r0 * 64]);
            }
            __syncthreads();

            // S = Q K^T (swizzled Ks read)
            f32x4 sf[4] = {};
            #pragma unroll
            for (int kt = 0; kt < 2; kt++)
                #pragma unroll
                for (int ni = 0; ni < 4; ni++) {
                    s16x8 kb = *(const s16x8*)&Ks[(ni * 16 + lr) * 64 + (((kt * 4 + lg) ^ (lr & 7)) * 8)];
                    sf[ni] = __builtin_amdgcn_mfma_f32_16x16x32_bf16(qf[kt], kb, sf[ni], 0, 0, 0);
                }

            const bool diag = (tt == nt - 1);
            #pragma unroll
            for (int ni = 0; ni < 4; ni++) {
                #pragma unroll
                for (int r = 0; r < 4; r++) {
                    float s = sf[ni][r];
                    if (diag) {
                        int qi = w * 16 + lg * 4 + r;
                        if (ni * 16 + lr > qi) s = -INFINITY;
                    }
                    float p = exp2f(__fmaf_rn(s, 0.18033688f, -17.3123405f));
                    union { float f; unsigned int u; } cv; cv.f = p;
                    Ps[w][lg * 4 + r][ni * 16 + lr] = (unsigned short)(cv.u >> 16);
                }
            }

            // O += P V (swizzled Vs read); l via ones-row fragment
            #pragma unroll
            for (int kt = 0; kt < 2; kt++) {
                s16x8 pa = *(const s16x8*)&Ps[w][lr][kt * 32 + lk];
                #pragma unroll
                for (int dt = 0; dt < 4; dt++) {
                    s16x8 vb = *(const s16x8*)&Vs[(dt * 16 + lr) * 64 + (((kt * 4 + lg) ^ (lr & 7)) * 8)];
                    o[dt] = __builtin_amdgcn_mfma_f32_16x16x32_bf16(pa, vb, o[dt], 0, 0, 0);
                }
                s16x8 vb4 = *(const s16x8*)&Ones[lr][kt * 32 + lk];
                o4 = __builtin_amdgcn_mfma_f32_16x16x32_bf16(pa, vb4, o4, 0, 0, 0);
            }
        }

        // normalize + write bf16 (l lives in lanes lr==0)
        #pragma unroll
        for (int r = 0; r < 4; r++) {
            float l = __shfl(o4[r], lane & 48);
            float invl = 1.0f / l;
            int qi = q0 + w * 16 + lg * 4 + r;
            #pragma unroll
            for (int dt = 0; dt < 4; dt++)
                out[(rowbase + qi) * HID + hoff + dt * 16 + lr] = f2bf(o[dt][r] * invl);
        }
    }
}

extern "C" void kernel_launch(void* const* d_in, const int* in_sizes, int n_in,
                              void* d_out, int out_size, void* d_ws, size_t ws_size,
                              hipStream_t stream) {
    const float* x      = (const float*)d_in[0];
    const float* w_attn = (const float*)d_in[1];
    const float* b_attn = (const float*)d_in[2];
    const float* w_proj = (const float*)d_in[3];
    const float* b_proj = (const float*)d_in[4];
    float* out = (float*)d_out;

    char* ws = (char*)d_ws;
    unsigned short* qkv      = (unsigned short*)(ws);               // 24 MB
    unsigned short* waT      = (unsigned short*)(ws + 25165824);    // 6 MB
    unsigned short* wpT      = (unsigned short*)(ws + 31457280);    // 2 MB
    unsigned short* attn_out = (unsigned short*)(ws + 33554432);    // 8 MB (bf16)
    unsigned short* xb       = (unsigned short*)(ws + 41943040);    // 8 MB (bf16)
    unsigned short* vTr      = (unsigned short*)(ws + 50331648);    // 8 MB (bf16)

    const int M = BATCH * S_LEN;   // 4096

    f32_to_bf16_kernel<<<dim3((M * HID / 8 + 255) / 256), 256, 0, stream>>>(x, xb, M * HID / 8);

    dim3 tb(32, 8);
    transpose_bf16_kernel<<<dim3(3 * HID / 32, HID / 32), tb, 0, stream>>>(w_attn, waT, HID, 3 * HID);
    transpose_bf16_kernel<<<dim3(HID / 32, HID / 32), tb, 0, stream>>>(w_proj, wpT, HID, HID);

    gemm_kernel<1><<<dim3(3 * HID / 128, M / 128), 256, 0, stream>>>(
        xb, waT, b_attn, (void*)qkv, M, 3 * HID, HID);

    vtrans_kernel<<<dim3(HID / 32, S_LEN / 32, BATCH), tb, 0, stream>>>(qkv, vTr);

    attn_kernel<<<dim3(16, NHEADS, BATCH), 256, 0, stream>>>(qkv, vTr, attn_out);

    gemm64_kernel<0><<<dim3(HID / 128, M / 64), 256, 0, stream>>>(
        attn_out, wpT, b_proj, out, M, HID, HID);
}